// Round 3
// baseline (151.899 us; speedup 1.0000x reference)
//
#include <hip/hip_runtime.h>

#define NPTS 65536
#define CCH  32
#define DDIM 64
#define GVOX (DDIM*DDIM*DDIM)   // B=1 -> 262144 voxels
#define MAXT 2080               // >= ceil(NPTS/32) + 27 (per-class padding)

typedef _Float16 half8   __attribute__((ext_vector_type(8)));
typedef _Float16 half4v  __attribute__((ext_vector_type(4)));
typedef float    floatx16 __attribute__((ext_vector_type(16)));

// ---------------- prep0: init + conversions (one launch) ----------------
// Weights are rewritten into MFMA B-fragment order:
//   frag index = t*1024 + h*512 + (kq*32 + cout)*8 + j   where cin = h*16+kq*8+j
// so a wave's B load is lane-sequential (conflict-free ds_read_b128 later).
__global__ __launch_bounds__(256) void k_prep0(
    int* __restrict__ map, int* __restrict__ sorted,
    const float* __restrict__ values, _Float16* __restrict__ valsh,
    const float* __restrict__ k1, const float* __restrict__ k2,
    _Float16* __restrict__ w1, _Float16* __restrict__ w2,
    _Float16* __restrict__ hh, int* __restrict__ pcoord,
    int* __restrict__ cnt, int* __restrict__ slot)
{
  int tid = blockIdx.x * 256 + threadIdx.x;
  if (tid < GVOX/4) { ((int4*)map)[tid] = make_int4(-1,-1,-1,-1); return; }
  tid -= GVOX/4;
  if (tid < MAXT*32/4) { ((int4*)sorted)[tid] = make_int4(NPTS,NPTS,NPTS,NPTS); return; }
  tid -= MAXT*32/4;
  if (tid < (NPTS*CCH)/4) {
    float4 v = ((const float4*)values)[tid];
    half4v h = { (_Float16)v.x, (_Float16)v.y, (_Float16)v.z, (_Float16)v.w };
    ((half4v*)valsh)[tid] = h; return;
  }
  tid -= (NPTS*CCH)/4;
  if (tid < 27*CCH*CCH) {
    int t = tid/(CCH*CCH), r = tid%(CCH*CCH);
    int cin = r/CCH, cout = r%CCH;
    int h = cin >> 4, kq = (cin >> 3) & 1, j = cin & 7;
    int dst = t*1024 + h*512 + (kq*32 + cout)*8 + j;
    w1[dst] = (_Float16)k1[tid]; w2[dst] = (_Float16)k2[tid]; return;
  }
  tid -= 27*CCH*CCH;
  if (tid < CCH) { valsh[NPTS*CCH+tid] = (_Float16)0.f; hh[NPTS*CCH+tid] = (_Float16)0.f; return; }
  tid -= CCH;
  if (tid < 27) { cnt[tid] = 0; slot[tid] = 0; return; }
  tid -= 27;
  if (tid == 0) pcoord[NPTS] = 0;               // sentinel
}
#define PREP0_THREADS (GVOX/4 + MAXT*32/4 + (NPTS*CCH)/4 + 27*CCH*CCH + CCH + 27 + 1)

// ---------------- prep1: map + pcoord + class histogram ----------------
__global__ __launch_bounds__(256) void k_prep1(const int* __restrict__ idx,
                                               int* __restrict__ map,
                                               int* __restrict__ pcoord,
                                               int* __restrict__ cls,
                                               int* __restrict__ cnt)
{
  __shared__ int lcnt[27];
  if (threadIdx.x < 27) lcnt[threadIdx.x] = 0;
  __syncthreads();
  const int n = blockIdx.x*256 + threadIdx.x;
  const int b = idx[4*n], z = idx[4*n+1], y = idx[4*n+2], x = idx[4*n+3];
  map[((b*DDIM + z)*DDIM + y)*DDIM + x] = n;
  pcoord[n] = (b<<18) | (z<<12) | (y<<6) | x;
  const int cz = (z==0)?0:((z==DDIM-1)?2:1);
  const int cy = (y==0)?0:((y==DDIM-1)?2:1);
  const int cx = (x==0)?0:((x==DDIM-1)?2:1);
  const int c = cz*9 + cy*3 + cx;
  cls[n] = c;
  atomicAdd(&lcnt[c], 1);
  __syncthreads();
  if (threadIdx.x < 27 && lcnt[threadIdx.x]) atomicAdd(&cnt[threadIdx.x], lcnt[threadIdx.x]);
}

// ---------------- prep2: tiny serial scan over 27 classes ----------------
__global__ void k_prep2(const int* __restrict__ cnt, int* __restrict__ clsbase,
                        int* __restrict__ tstart, int* __restrict__ ntiles)
{
  if (threadIdx.x == 0 && blockIdx.x == 0) {
    int b = 0, tb = 0;
    for (int c = 0; c < 27; ++c) {
      clsbase[c] = b; tstart[c] = tb;
      int nt = (cnt[c] + 31) >> 5;    // 32-point tiles
      b += nt << 5; tb += nt;
    }
    tstart[27] = tb; *ntiles = tb;
  }
}

// ---------------- prep3: scatter into class-sorted order + tile classes -----
__global__ __launch_bounds__(256) void k_prep3(const int* __restrict__ cls,
                                               const int* __restrict__ clsbase,
                                               int* __restrict__ slot,
                                               int* __restrict__ sorted,
                                               const int* __restrict__ tstart,
                                               const int* __restrict__ ntp,
                                               int* __restrict__ tileclass)
{
  if (blockIdx.x < NPTS/256) {
    __shared__ int lcnt[27], lbase[27];
    if (threadIdx.x < 27) lcnt[threadIdx.x] = 0;
    __syncthreads();
    const int n = blockIdx.x*256 + threadIdx.x;
    const int c = cls[n];
    const int lrank = atomicAdd(&lcnt[c], 1);
    __syncthreads();
    if (threadIdx.x < 27)
      lbase[threadIdx.x] = lcnt[threadIdx.x] ? atomicAdd(&slot[threadIdx.x], lcnt[threadIdx.x]) : 0;
    __syncthreads();
    sorted[clsbase[c] + lbase[c] + lrank] = n;
  } else {
    const int i = (blockIdx.x - NPTS/256)*256 + threadIdx.x;
    if (i >= MAXT) return;
    const int nt = *ntp;
    int c = 13;
    if (i < nt) {
      for (int cc = 0; cc < 27; ++cc)
        if (i >= tstart[cc] && i < tstart[cc+1]) { c = cc; break; }
    }
    tileclass[i] = c;
  }
}

// ---------------- nbr: resolve each point's 27 clamped sources once ---------
__global__ __launch_bounds__(256) void k_nbr(const int* __restrict__ sorted,
                                             const int* __restrict__ pcoord,
                                             const int* __restrict__ map,
                                             int* __restrict__ nbr)
{
  const int i = blockIdx.x*256 + threadIdx.x;
  if (i >= MAXT*32) return;
  const int tile = i >> 5, m = i & 31;
  const int pid = sorted[i];
  const int pc  = pcoord[pid];                  // sentinel row -> (0,0,0), harmless
  const int bb = pc>>18, z = (pc>>12)&63, y = (pc>>6)&63, x = pc&63;
  const int linb = bb << 18;
  const int az[3] = { max(z-1,0)<<12, z<<12, min(z+1,DDIM-1)<<12 };
  const int ay[3] = { max(y-1,0)<<6,  y<<6,  min(y+1,DDIM-1)<<6 };
  const int ax[3] = { max(x-1,0),     x,     min(x+1,DDIM-1) };
#pragma unroll
  for (int j = 0; j < 27; ++j) {
    int src = map[linb | az[j/9] | ay[(j/3)%3] | ax[j%3]];
    nbr[(tile*27 + j)*32 + m] = (src < 0) ? NPTS : src;
  }
}

// ---------------- unified conv: LDS-staged B, coalesced nbr, 32x32x16 MFMA --
template<int MODE>
__global__ __launch_bounds__(256) void conv32(
    const _Float16* __restrict__ A,        // (NPTS+1) x 32 f16, row NPTS = zeros
    const int* __restrict__ sorted,
    const int* __restrict__ tileclass,
    const int* __restrict__ nbr,
    const int* __restrict__ ntp,
    const _Float16* __restrict__ wfrag,    // 27 taps x 1024 halves, fragment order
    const float* __restrict__ bias,
    const float* __restrict__ mask,
    const float* __restrict__ resid,
    _Float16* __restrict__ hout,
    float* __restrict__ fout)
{
  __shared__ _Float16 bs[27*1024];         // 55,296 B
  {
    const int4* s = (const int4*)wfrag;
    int4* d = (int4*)bs;
#pragma unroll
    for (int i = 0; i < 14; ++i) {
      const int o = threadIdx.x + i*256;
      if (o < 27*1024/8) d[o] = s[o];
    }
  }
  __syncthreads();

  const int tile = blockIdx.x*4 + (threadIdx.x >> 6);
  if (tile >= *ntp) return;
  const int lane = threadIdx.x & 63;
  const int m = lane & 31, kh = lane >> 5;
  const int scls = __builtin_amdgcn_readfirstlane(tileclass[tile]);
  const int cz = scls/9, cy = (scls/3)%3, cx = scls%3;

  int nb[27];
#pragma unroll
  for (int j = 0; j < 27; ++j) nb[j] = nbr[(tile*27 + j)*32 + m];

  floatx16 acc = {};
#pragma unroll
  for (int j = 0; j < 27; ++j) {
    const int jz = j/9, jy = (j/3)%3, jx = j%3;
    const int tz = (cz==1) ? (2-jz) : ((jz==1) ? 1 : ((cz==0) ? 0 : 2));
    const int ty = (cy==1) ? (2-jy) : ((jy==1) ? 1 : ((cy==0) ? 0 : 2));
    const int tx = (cx==1) ? (2-jx) : ((jx==1) ? 1 : ((cx==0) ? 0 : 2));
    const int t  = tz*9 + ty*3 + tx;
    const _Float16* ap = A + nb[j]*CCH + kh*8;
    half8 alo = *(const half8*)ap;           // k = 0..15 (this lane's 8)
    half8 ahi = *(const half8*)(ap + 16);    // k = 16..31
    const _Float16* bp = bs + t*1024 + lane*8;
    half8 blo = *(const half8*)bp;
    half8 bhi = *(const half8*)(bp + 512);
    acc = __builtin_amdgcn_mfma_f32_32x32x16_f16(alo, blo, acc, 0, 0, 0);
    acc = __builtin_amdgcn_mfma_f32_32x32x16_f16(ahi, bhi, acc, 0, 0, 0);
  }

  // D layout: col = lane&31 (cout), row = (reg&3) + 8*(reg>>2) + 4*(lane>>5)
  const float bi = bias[m];
#pragma unroll
  for (int r = 0; r < 16; ++r) {
    const int row = (r&3) + 8*(r>>2) + 4*kh;
    const int pr  = sorted[tile*32 + row];
    if (pr >= NPTS) continue;                // padded row
    const float mk = mask[pr];
    const float v = (acc[r] + mk*bi) * mk;
    if (MODE == 0) hout[pr*CCH + m] = (_Float16)fmaxf(v, 0.f);
    else           fout[pr*CCH + m] = resid[pr*CCH + m] + v;
  }
}

// ---------------- launch ----------------

extern "C" void kernel_launch(void* const* d_in, const int* in_sizes, int n_in,
                              void* d_out, int out_size, void* d_ws, size_t ws_size,
                              hipStream_t stream) {
  const float* values = (const float*)d_in[0];
  const int*   indices= (const int*)  d_in[1];
  const float* maskv  = (const float*)d_in[2];
  const float* kern1  = (const float*)d_in[3];
  const float* bias1  = (const float*)d_in[4];
  const float* kern2  = (const float*)d_in[5];
  const float* bias2  = (const float*)d_in[6];
  float* out = (float*)d_out;

  char* ws = (char*)d_ws;
  size_t off = 0;
  auto alloc = [&](size_t bytes) { void* p = ws + off; off = (off + bytes + 255) & ~(size_t)255; return p; };
  int*      map      = (int*)     alloc(GVOX*4);
  int*      pcoord   = (int*)     alloc((NPTS+1)*4);
  int*      cls      = (int*)     alloc(NPTS*4);
  int*      sorted   = (int*)     alloc(MAXT*32*4);
  int*      tileclass= (int*)     alloc(MAXT*4);
  int*      nbr      = (int*)     alloc((size_t)MAXT*27*32*4);   // 7.2 MB
  int*      cnt      = (int*)     alloc(27*4);
  int*      slot     = (int*)     alloc(27*4);
  int*      clsbase  = (int*)     alloc(27*4);
  int*      tstart   = (int*)     alloc(28*4);
  int*      ntiles   = (int*)     alloc(4);
  _Float16* valsh    = (_Float16*)alloc((NPTS+1)*CCH*2);
  _Float16* hh       = (_Float16*)alloc((NPTS+1)*CCH*2);
  _Float16* wf1      = (_Float16*)alloc(27*1024*2);
  _Float16* wf2      = (_Float16*)alloc(27*1024*2);

  k_prep0<<<(PREP0_THREADS + 255)/256, 256, 0, stream>>>(
      map, sorted, values, valsh, kern1, kern2, wf1, wf2, hh, pcoord, cnt, slot);
  k_prep1<<<NPTS/256, 256, 0, stream>>>(indices, map, pcoord, cls, cnt);
  k_prep2<<<1, 64, 0, stream>>>(cnt, clsbase, tstart, ntiles);
  k_prep3<<<NPTS/256 + (MAXT+255)/256, 256, 0, stream>>>(
      cls, clsbase, slot, sorted, tstart, ntiles, tileclass);
  k_nbr  <<<(MAXT*32)/256, 256, 0, stream>>>(sorted, pcoord, map, nbr);

  conv32<0><<<MAXT/4, 256, 0, stream>>>(valsh, sorted, tileclass, nbr, ntiles,
                                        wf1, bias1, maskv, nullptr, hh, nullptr);
  conv32<1><<<MAXT/4, 256, 0, stream>>>(hh, sorted, tileclass, nbr, ntiles,
                                        wf2, bias2, maskv, values, nullptr, out);
}